// Round 6
// baseline (42.708 us; speedup 1.0000x reference)
//
#include <hip/hip_runtime.h>
#include <hip/hip_fp16.h>

// Problem geometry (fixed by the reference)
#define NROWS   32768      // out_features N
#define KTOT    8192       // in_features K
#define KP      1024       // packed bytes per row (each stored as one int32 on device)
#define GROUPS  64         // scale groups per row (K/128)

// Split-K byte-LUT design
#define SLICE_W 256        // weights per K-slice
#define SLICE_B 32         // packed bytes (int32 elements) per slice per row
#define NSLICES (KTOT / SLICE_W)        // 32
#define BLK     512        // threads per block (8 waves)
#define ROWS_PER_BLK 1024
#define RCHUNKS (NROWS / ROWS_PER_BLK)  // 32  -> grid 1024 = 4 blocks/CU exact
#define LUTPAD  264        // build-write bank spread (2-way, free)

// ---------------------------------------------------------------------------
// Pass 1: SCALED per-(row, group) partials -> pTh[g*NROWS + r] (__half).
// One block = one K-slice (2 groups) x 1024 rows. 33 KiB byte-LUT in LDS.
// Scales are read here (scattered 8B/row; absorbed by L2/IC since the 8
// sharer-blocks of each 64B line are dispatched concurrently) so pass2
// becomes a pure sum. Inner loop: 4-deep explicit load pipeline.
// ---------------------------------------------------------------------------
__global__ __launch_bounds__(BLK, 8)
void bitlin_partials(const float* __restrict__ x,
                     const int* __restrict__ packed,
                     const float* __restrict__ scales,
                     __half* __restrict__ pTh)
{
    __shared__ float lut[SLICE_B][LUTPAD];

    const int s     = blockIdx.x & (NSLICES - 1);  // K-slice id
    const int chunk = blockIdx.x >> 5;             // row-chunk id
    const int tid   = threadIdx.x;

    // ---- Gray-code LUT build: thread owns (pos, low-nibble L), walks the
    // high nibble in reflected-Gray order (1 add per entry).
    {
        const int pos = tid >> 4;          // byte position in slice, 0..31
        const int L   = tid & 15;          // low-nibble value this thread owns
        float xs[8];
#pragma unroll
        for (int i = 0; i < 8; ++i) xs[i] = x[s * SLICE_W + pos * 8 + i];
        float e = ((L & 1) ? xs[0] : -xs[0])
                + ((L & 2) ? xs[1] : -xs[1])
                + ((L & 4) ? xs[2] : -xs[2])
                + ((L & 8) ? xs[3] : -xs[3])
                - xs[4] - xs[5] - xs[6] - xs[7];
        const float t0 = 2.f * xs[4], t1 = 2.f * xs[5],
                    t2 = 2.f * xs[6], t3 = 2.f * xs[7];
        float* row = &lut[pos][L];         // entries at row[G*16], byte = G<<4|L
        row[ 0*16] = e;                    // Gray walk of high nibble G
        e += t0; row[ 1*16] = e;
        e += t1; row[ 3*16] = e;
        e -= t0; row[ 2*16] = e;
        e += t2; row[ 6*16] = e;
        e += t0; row[ 7*16] = e;
        e -= t1; row[ 5*16] = e;
        e -= t0; row[ 4*16] = e;
        e += t3; row[12*16] = e;
        e += t0; row[13*16] = e;
        e += t1; row[15*16] = e;
        e -= t0; row[14*16] = e;
        e -= t2; row[10*16] = e;
        e += t0; row[11*16] = e;
        e -= t1; row[ 9*16] = e;
        e -= t0; row[ 8*16] = e;
    }
    __syncthreads();

    const int lane = tid & 63;
    const int wave = tid >> 6;       // 0..7
    const int sub  = lane & 7;       // which int4 (4 packed bytes) in the slice-row
    const int rsub = lane >> 3;      // row-within-8 for this wave-iteration
    const int rowBase = chunk * ROWS_PER_BLK + wave * (ROWS_PER_BLK / 8);
    const int pos0 = sub * 4;
    const int gcol = s * 2 + (sub >> 2);            // this lane-group's scale col

    const int4* __restrict__ p4 = (const int4*)packed;  // 4 packed bytes per int4

#pragma unroll
    for (int tt = 0; tt < 4; ++tt) {
        // ---- issue 4 independent packed loads + 4 scale loads up front
        int4  v[4];
        float sc[4];
        int   r[4];
#pragma unroll
        for (int j = 0; j < 4; ++j) {
            r[j]  = rowBase + (tt * 4 + j) * 8 + rsub;
            v[j]  = p4[r[j] * (KP / 4) + s * (SLICE_B / 4) + sub];
            sc[j] = scales[r[j] * GROUPS + gcol];   // 8B/row, L2/IC-absorbed
        }
        // ---- consume
#pragma unroll
        for (int j = 0; j < 4; ++j) {
            float acc = lut[pos0 + 0][v[j].x & 255]
                      + lut[pos0 + 1][v[j].y & 255]
                      + lut[pos0 + 2][v[j].z & 255]
                      + lut[pos0 + 3][v[j].w & 255];
            acc *= sc[j];                 // sc uniform within each 4-lane group
            // butterfly over the 4 lanes covering one group (128 weights)
            acc += __shfl_xor(acc, 1);
            acc += __shfl_xor(acc, 2);
            if ((sub & 3) == 0)           // lanes sub==0 (g=2s) and sub==4 (g=2s+1)
                pTh[gcol * NROWS + r[j]] = __float2half_rn(acc);
        }
    }
}

// ---------------------------------------------------------------------------
// Pass 2: pure sum over 64 scaled fp16 partials. out[r] = sum_g pTh[g*N + r].
// 64 blocks x 256 threads, each thread owns 2 rows via __half2 (coalesced).
// pTh is L2/IC-warm (written by pass1, 4.2 MB).
// ---------------------------------------------------------------------------
__global__ __launch_bounds__(256)
void bitlin_sum(const __half2* __restrict__ pTh2, float2* __restrict__ out2)
{
    const int rp = blockIdx.x * 256 + threadIdx.x;   // half2 index (2 rows)
    float a0 = 0.f, a1 = 0.f;
#pragma unroll
    for (int g = 0; g < GROUPS; ++g) {
        const float2 f = __half22float2(pTh2[(size_t)g * (NROWS / 2) + rp]);
        a0 += f.x;
        a1 += f.y;
    }
    out2[rp] = make_float2(a0, a1);
}

// ---------------------------------------------------------------------------
// Fallback (proven Round-2 path) if ws can't hold the 4.2 MB partial matrix.
// ---------------------------------------------------------------------------
__global__ __launch_bounds__(BLK, 4)
void bitlin_main_atomic(const float* __restrict__ x,
                        const int* __restrict__ packed,
                        const float* __restrict__ scales,
                        float* __restrict__ ws)
{
    __shared__ float lut[SLICE_B][256];
    const int s     = blockIdx.x & (NSLICES - 1);
    const int chunk = blockIdx.x >> 5;
    const int tid   = threadIdx.x;
    {
        const int pos = tid >> 4;
        const int b0  = (tid & 15) << 4;
        float xs[8];
#pragma unroll
        for (int i = 0; i < 8; ++i) xs[i] = x[s * SLICE_W + pos * 8 + i];
#pragma unroll
        for (int b = 0; b < 16; ++b) {
            const int byte = b0 + b;
            float v = 0.f;
#pragma unroll
            for (int i = 0; i < 8; ++i)
                v += ((byte >> i) & 1) ? xs[i] : -xs[i];
            lut[pos][byte] = v;
        }
    }
    __syncthreads();

    const int lane = tid & 63;
    const int wave = tid >> 6;
    const int sub  = lane & 7;
    const int rsub = lane >> 3;
    const int rowBase = chunk * 512 + wave * 64;
    const int4* __restrict__ p4 = (const int4*)packed;

#pragma unroll
    for (int t = 0; t < 8; ++t) {
        const int r = rowBase + t * 8 + rsub;
        const int4 v = p4[r * (KP / 4) + s * (SLICE_B / 4) + sub];
        const float sc = scales[r * GROUPS + s * 2 + (sub >> 2)];
        const int pos0 = sub * 4;
        float acc = lut[pos0 + 0][v.x & 255]
                  + lut[pos0 + 1][v.y & 255]
                  + lut[pos0 + 2][v.z & 255]
                  + lut[pos0 + 3][v.w & 255];
        acc *= sc;
        acc += __shfl_xor(acc, 1);
        acc += __shfl_xor(acc, 2);
        acc += __shfl_xor(acc, 4);
        if (sub == 0) atomicAdd(&ws[r], acc);
    }
}

__global__ __launch_bounds__(512)
void bitlin_fin(const float* __restrict__ ws, float* __restrict__ out)
{
    const int i = blockIdx.x * blockDim.x + threadIdx.x;
    out[i] = ws[i];
}

extern "C" void kernel_launch(void* const* d_in, const int* in_sizes, int n_in,
                              void* d_out, int out_size, void* d_ws, size_t ws_size,
                              hipStream_t stream)
{
    const float* x      = (const float*)d_in[0];
    const int*   packed = (const int*)d_in[1];
    const float* scales = (const float*)d_in[2];

    const size_t pTh_bytes = (size_t)GROUPS * NROWS * sizeof(__half);  // 4.2 MB

    if (ws_size >= pTh_bytes) {
        __half* pTh = (__half*)d_ws;
        bitlin_partials<<<dim3(NSLICES * RCHUNKS), dim3(BLK), 0, stream>>>(x, packed, scales, pTh);
        bitlin_sum<<<dim3(NROWS / 512), dim3(256), 0, stream>>>((const __half2*)pTh, (float2*)d_out);
    } else {
        // fallback: proven Round-2 fused path
        float* ws = (float*)d_ws;
        hipMemsetAsync(ws, 0, NROWS * sizeof(float), stream);
        bitlin_main_atomic<<<dim3(NSLICES * (NROWS / 512)), dim3(BLK), 0, stream>>>(x, packed, scales, ws);
        bitlin_fin<<<dim3(NROWS / 512), dim3(512), 0, stream>>>(ws, (float*)d_out);
    }
}

// Round 7
// 30.129 us; speedup vs baseline: 1.4175x; 1.4175x over previous
//
#include <hip/hip_runtime.h>
#include <hip/hip_fp16.h>

// Problem geometry (fixed by the reference)
#define NROWS   32768      // out_features N
#define KTOT    8192       // in_features K
#define KP      1024       // packed bytes per row (each stored as one int32 on device)
#define GROUPS  64         // scale groups per row (K/128)

// Split-K design: 512-weight slices + sign-symmetric 128-entry byte-LUT
#define SLICE_W 512        // weights per K-slice
#define SLICE_I 64         // int32 elements per slice per row
#define NSLICES (KTOT / SLICE_W)        // 16
#define BLK     512        // threads per block (8 waves)
#define ROWS_PER_BLK 512
#define RCHUNKS (NROWS / ROWS_PER_BLK)  // 64 -> grid 1024 = 4 blocks/CU
#define LUTW    132        // 128 entries + 4 pad (bank spread)

// ---------------------------------------------------------------------------
// Pass 1: per-(row, group) UNSCALED partials -> pTh[g*NROWS + r] (__half).
// One block = one 512-weight K-slice (4 groups) x 512 rows.
// Sign-symmetric LUT: dot(b) = -dot(b ^ 0xFF), store only idx<128 (33 KiB).
// Each row-slice read is 256 B contiguous (2x the old 128 B granule).
// ---------------------------------------------------------------------------
__global__ __launch_bounds__(BLK, 8)
void bitlin_partials(const float* __restrict__ x,
                     const int* __restrict__ packed,
                     __half* __restrict__ pTh)
{
    __shared__ float lut[SLICE_W / 8][LUTW];   // 64 positions x 128 entries

    const int s     = blockIdx.x & (NSLICES - 1);  // K-slice id (0..15)
    const int chunk = blockIdx.x >> 4;             // row-chunk id (0..63)
    const int tid   = threadIdx.x;

    // ---- Build half-LUT: thread owns (pos = tid>>3, high-3-bits h = tid&7),
    // Gray-walks the low nibble (1 add per entry). idx bits: 0..3 -> x0..x3,
    // 4..6 -> x4..x6; bit7 == 0 => x7 coefficient always -1.
    {
        const int pos = tid >> 3;          // 0..63
        const int h   = tid & 7;           // high 3 bits of the 7-bit index
        float xs[8];
#pragma unroll
        for (int i = 0; i < 8; ++i) xs[i] = x[s * SLICE_W + pos * 8 + i];
        float e = -xs[0] - xs[1] - xs[2] - xs[3]
                + ((h & 1) ? xs[4] : -xs[4])
                + ((h & 2) ? xs[5] : -xs[5])
                + ((h & 4) ? xs[6] : -xs[6])
                - xs[7];
        const float t0 = 2.f * xs[0], t1 = 2.f * xs[1],
                    t2 = 2.f * xs[2], t3 = 2.f * xs[3];
        float* row = &lut[pos][h << 4];    // entries at row[l], idx = h*16+l
        row[ 0] = e;                       // Gray walk of low nibble:
        e += t0; row[ 1] = e;              // 0,1,3,2,6,7,5,4,12,13,15,14,10,11,9,8
        e += t1; row[ 3] = e;
        e -= t0; row[ 2] = e;
        e += t2; row[ 6] = e;
        e += t0; row[ 7] = e;
        e -= t1; row[ 5] = e;
        e -= t0; row[ 4] = e;
        e += t3; row[12] = e;
        e += t0; row[13] = e;
        e += t1; row[15] = e;
        e -= t0; row[14] = e;
        e -= t2; row[10] = e;
        e += t0; row[11] = e;
        e -= t1; row[ 9] = e;
        e -= t0; row[ 8] = e;
    }
    __syncthreads();

    const int lane = tid & 63;
    const int wave = tid >> 6;        // 0..7
    const int sub  = lane & 15;       // which int4 within the 256B row-slice
    const int rsub = lane >> 4;       // row-within-4 for this wave-iteration
    const int rowBase = chunk * ROWS_PER_BLK + wave * (ROWS_PER_BLK / 8);
    const int pos0 = sub * 4;         // byte position of this int4's first byte
    const int g    = s * 4 + (sub >> 2);   // global scale-group of this lane

    const int4* __restrict__ p4 = (const int4*)packed;

#pragma unroll 4
    for (int t = 0; t < 16; ++t) {
        const int r = rowBase + t * 4 + rsub;
        // 16 lanes cover one row's 256 B slice; 4 rows per wave-load
        const int4 v = p4[r * (KP / 4) + s * (SLICE_I / 4) + sub];
        float acc = 0.f;
        const int bb[4] = { v.x & 255, v.y & 255, v.z & 255, v.w & 255 };
#pragma unroll
        for (int j = 0; j < 4; ++j) {
            const int b   = bb[j];
            const int m   = b >> 7;                    // 0 or 1
            const int idx = (b ^ (-m)) & 127;          // complement if bit7
            const float val = lut[pos0 + j][idx];
            acc += __int_as_float(__float_as_int(val) ^ (m << 31));
        }
        // butterfly over the 4 lanes covering one group (128 weights)
        acc += __shfl_xor(acc, 1);
        acc += __shfl_xor(acc, 2);
        if ((sub & 3) == 0)            // leaders: sub = 0,4,8,12 -> groups 4s..4s+3
            pTh[g * NROWS + r] = __float2half_rn(acc);
    }
}

// ---------------------------------------------------------------------------
// Pass 2 (proven Round-4 kernel, verbatim): out[r] = sum_g pTh[g*N+r]*sc[r][g]
// Block = 512 threads x 64 rows; coalesced reads; scales staged in padded LDS.
// ---------------------------------------------------------------------------
__global__ __launch_bounds__(512)
void bitlin_scale(const __half* __restrict__ pTh,
                  const float* __restrict__ scales,
                  float* __restrict__ out)
{
    __shared__ float s_s[64][65];    // padded: conflict-free column reads
    __shared__ float s_part[64][9];  // per-(row, wave) partials, padded

    const int tid     = threadIdx.x;
    const int lane    = tid & 63;
    const int wave    = tid >> 6;
    const int rowBase = blockIdx.x * 64;

    const float4* s4 = (const float4*)(scales + (size_t)rowBase * GROUPS);
#pragma unroll
    for (int i = 0; i < 2; ++i) {
        const int idx = i * 512 + tid;
        const float4 v = s4[idx];
        const int r = idx >> 4;
        const int c = (idx & 15) * 4;
        s_s[r][c + 0] = v.x;
        s_s[r][c + 1] = v.y;
        s_s[r][c + 2] = v.z;
        s_s[r][c + 3] = v.w;
    }
    __syncthreads();

    const int r = rowBase + lane;
    float acc = 0.f;
#pragma unroll
    for (int i = 0; i < 8; ++i) {
        const int g = wave * 8 + i;
        acc += __half2float(pTh[(size_t)g * NROWS + r]) * s_s[lane][g];
    }
    s_part[lane][wave] = acc;
    __syncthreads();

    if (wave == 0) {
        float a = 0.f;
#pragma unroll
        for (int w = 0; w < 8; ++w) a += s_part[lane][w];
        out[r] = a;
    }
}

// ---------------------------------------------------------------------------
// Fallback (proven Round-2 path) if ws can't hold the 4.2 MB partial matrix.
// ---------------------------------------------------------------------------
__global__ __launch_bounds__(BLK, 4)
void bitlin_main_atomic(const float* __restrict__ x,
                        const int* __restrict__ packed,
                        const float* __restrict__ scales,
                        float* __restrict__ ws)
{
    __shared__ float lut[32][256];
    const int s     = blockIdx.x & 31;
    const int chunk = blockIdx.x >> 5;
    const int tid   = threadIdx.x;
    {
        const int pos = tid >> 4;
        const int b0  = (tid & 15) << 4;
        float xs[8];
#pragma unroll
        for (int i = 0; i < 8; ++i) xs[i] = x[s * 256 + pos * 8 + i];
#pragma unroll
        for (int b = 0; b < 16; ++b) {
            const int byte = b0 + b;
            float v = 0.f;
#pragma unroll
            for (int i = 0; i < 8; ++i)
                v += ((byte >> i) & 1) ? xs[i] : -xs[i];
            lut[pos][byte] = v;
        }
    }
    __syncthreads();

    const int lane = tid & 63;
    const int wave = tid >> 6;
    const int sub  = lane & 7;
    const int rsub = lane >> 3;
    const int rowBase = chunk * 512 + wave * 64;
    const int4* __restrict__ p4 = (const int4*)packed;

#pragma unroll
    for (int t = 0; t < 8; ++t) {
        const int r = rowBase + t * 8 + rsub;
        const int4 v = p4[r * (KP / 4) + s * 8 + sub];
        const float sc = scales[r * GROUPS + s * 2 + (sub >> 2)];
        const int pos0 = sub * 4;
        float acc = lut[pos0 + 0][v.x & 255]
                  + lut[pos0 + 1][v.y & 255]
                  + lut[pos0 + 2][v.z & 255]
                  + lut[pos0 + 3][v.w & 255];
        acc *= sc;
        acc += __shfl_xor(acc, 1);
        acc += __shfl_xor(acc, 2);
        acc += __shfl_xor(acc, 4);
        if (sub == 0) atomicAdd(&ws[r], acc);
    }
}

__global__ __launch_bounds__(512)
void bitlin_fin(const float* __restrict__ ws, float* __restrict__ out)
{
    const int i = blockIdx.x * blockDim.x + threadIdx.x;
    out[i] = ws[i];
}

extern "C" void kernel_launch(void* const* d_in, const int* in_sizes, int n_in,
                              void* d_out, int out_size, void* d_ws, size_t ws_size,
                              hipStream_t stream)
{
    const float* x      = (const float*)d_in[0];
    const int*   packed = (const int*)d_in[1];
    const float* scales = (const float*)d_in[2];

    const size_t pTh_bytes = (size_t)GROUPS * NROWS * sizeof(__half);  // 4.2 MB

    if (ws_size >= pTh_bytes) {
        __half* pTh = (__half*)d_ws;
        bitlin_partials<<<dim3(NSLICES * RCHUNKS), dim3(BLK), 0, stream>>>(x, packed, pTh);
        bitlin_scale<<<dim3(NROWS / 64), dim3(512), 0, stream>>>(pTh, scales, (float*)d_out);
    } else {
        // fallback: proven Round-2 fused path
        float* ws = (float*)d_ws;
        hipMemsetAsync(ws, 0, NROWS * sizeof(float), stream);
        bitlin_main_atomic<<<dim3(32 * (NROWS / 512)), dim3(BLK), 0, stream>>>(x, packed, scales, ws);
        bitlin_fin<<<dim3(NROWS / 512), dim3(512), 0, stream>>>(ws, (float*)d_out);
    }
}